// Round 7
// baseline (305.394 us; speedup 1.0000x reference)
//
#include <hip/hip_runtime.h>
#include <hip/hip_bf16.h>
#include <stdint.h>

typedef float f32x4 __attribute__((ext_vector_type(4)));
typedef short bf16x8 __attribute__((ext_vector_type(8)));
typedef unsigned short u16;

static constexpr int kB  = 16384;
static constexpr int kDC = 2048;
static constexpr int kNF = 768;
static constexpr float kEps = 1e-5f;

// ---- workspace layout (bytes). Region X (OFF_X) holds H after gemmH.
static constexpr size_t OFF_FEATS  = 0;                       // [3][B][768] bf16
static constexpr size_t OFF_X      = 75497472;                // H [3*B][128] f32
static constexpr size_t OFF_WCBF   = OFF_X + 67108864;
static constexpr size_t OFF_WA1BF  = OFF_WCBF + 3145728;
static constexpr size_t OFF_W1BF   = OFF_WA1BF + 196608;
static constexpr size_t OFF_FUSE   = OFF_W1BF + 1179648;      // [B][256] f32
static constexpr size_t OFF_SCORES = OFF_FUSE + 16777216;     // [B][3] f32
static constexpr size_t OFF_STATS  = OFF_SCORES + 196608;     // 3072 + 2048

static __device__ __forceinline__ u16 f2bf(float x) {
  union { float f; unsigned u; } c; c.f = x;
  unsigned r = c.u + 0x7fffu + ((c.u >> 16) & 1u);
  return (u16)(r >> 16);
}

static __device__ __forceinline__ unsigned pk2(float lo, float hi) {
  union { __hip_bfloat162 h; unsigned u; } c;
  c.h = __float22bfloat162_rn(make_float2(lo, hi));
  return c.u;
}

// batched convert: 8 independent loads in flight, then 8 stores
static __device__ __forceinline__ void cvt8x4(const float* __restrict__ in,
                                              u16* __restrict__ out, long base) {
  float4 f[8];
#pragma unroll
  for (int i = 0; i < 8; ++i) f[i] = ((const float4*)in)[base + i * 256];
#pragma unroll
  for (int i = 0; i < 8; ++i)
    ((ushort4*)out)[base + i * 256] =
        make_ushort4(f2bf(f[i].x), f2bf(f[i].y), f2bf(f[i].z), f2bf(f[i].w));
}

// ---------------- prep_w: fp32 -> bf16 for weights only (Wc, Wa1, W1) ----------------
// 256 threads x 8 float4. Wc 393,216 f4 -> 192 blk | Wa1 24,576 -> 12 | W1 147,456 -> 72  = 276
__global__ __launch_bounds__(256) void prep_w(
    const float* __restrict__ Wc, const float* __restrict__ Wa1, const float* __restrict__ W1,
    u16* __restrict__ wcbf, u16* __restrict__ wa1bf, u16* __restrict__ w1bf)
{
  const int b = blockIdx.x, t = threadIdx.x;
  const float* in; u16* out; long base;
  if (b < 192)      { in = Wc;  out = wcbf;  base = (long)b * 2048 + t; }
  else if (b < 204) { in = Wa1; out = wa1bf; base = (long)(b - 192) * 2048 + t; }
  else              { in = W1;  out = w1bf;  base = (long)(b - 204) * 2048 + t; }
  cvt8x4(in, out, base);
}

static __device__ __forceinline__ void gload16(const void* g, void* l) {
  __builtin_amdgcn_global_load_lds(
      (const __attribute__((address_space(1))) void*)g,
      (__attribute__((address_space(3))) void*)l, 16, 0, 0);
}

// ---------------- mega: GEMM1 (fp32-A reg-staged) + xb/xf convert blocks ----------------
// grid: 768 GEMM blocks (bx=id&127 M-tile, by=id>>7 N-tile 0..5) + 1536 xb + 512 xf = 2816
// GEMM: ctx = xc(f32) @ Wc^T(bf16) + bc -> bf16 feats[0]; A cvt_pk'd in-kernel (no xc roundtrip).
__global__ __launch_bounds__(256) void gemm_mega(
    const float* __restrict__ A, const u16* __restrict__ B,
    const float* __restrict__ bias, u16* __restrict__ C,
    const float* __restrict__ xb, const float* __restrict__ xf,
    u16* __restrict__ feats)
{
  __shared__ __align__(16) u16 As[128 * 32];
  __shared__ __align__(16) u16 Bs[128 * 32];
  const int id = blockIdx.x, t = threadIdx.x;

  if (id >= 768) {
    const int c = id - 768;
    if (c < 1536) {                       // xb -> feats[1]
      cvt8x4(xb, feats + (size_t)kB * kNF, (long)c * 2048 + t);
    } else {                              // xf -> feats[2] with repeat(3)
      const long base = (long)(c - 1536) * 2048 + t;
      float4 f[8];
#pragma unroll
      for (int i = 0; i < 8; ++i) f[i] = ((const float4*)xf)[base + i * 256];
#pragma unroll
      for (int i = 0; i < 8; ++i) {
        const long v = base + i * 256;
        u16 e0 = f2bf(f[i].x), e1 = f2bf(f[i].y), e2 = f2bf(f[i].z), e3 = f2bf(f[i].w);
        size_t p = (size_t)v * 4;
        size_t row = p >> 8;
        int col = (int)(p & 255);
        u16* o = feats + (size_t)2 * kB * kNF + row * kNF + col * 3;
        ushort4* o4 = (ushort4*)o;
        o4[0] = make_ushort4(e0, e0, e0, e1);
        o4[1] = make_ushort4(e1, e1, e2, e2);
        o4[2] = make_ushort4(e2, e3, e3, e3);
      }
    }
    return;
  }

  // ---- GEMM path (round-2-verified gemm_a32 structure) ----
  const int bx = id & 127, by = id >> 7;
  const size_t m0 = (size_t)bx * 128;
  const int n0 = by * 128;
  const int lane = t & 63, wave = t >> 6;
  const int wm = (wave >> 1) * 64, wn = (wave & 1) * 64;
  const int fr = lane & 15, fq = lane >> 4;

  const int srow = t >> 2, scol = (t & 3) * 8;
  const u16* gb0 = B + (size_t)(n0 + srow) * kDC + scol;
  const u16* gb1 = B + (size_t)(n0 + 64 + srow) * kDC + scol;
  u16* lb = Bs + t * 8;

  const int arow = t >> 1, ah = (t & 1);
  const float* ga = A + (m0 + arow) * (size_t)kDC + ah * 16;
  u16* lawr = As + arow * 32 + ah * 16;

  const u16* fa = As + (wm + fr) * 32 + fq * 8;
  const u16* fb = Bs + (wn + fr) * 32 + fq * 8;

  f32x4 acc[4][4] = {};
  float4 ra0, ra1, ra2, ra3;
  auto loadA = [&]() {
    ra0 = ((const float4*)ga)[0]; ra1 = ((const float4*)ga)[1];
    ra2 = ((const float4*)ga)[2]; ra3 = ((const float4*)ga)[3];
  };
  auto cvtWrite = [&]() {
    uint4 w0, w1;
    w0.x = pk2(ra0.x, ra0.y); w0.y = pk2(ra0.z, ra0.w);
    w0.z = pk2(ra1.x, ra1.y); w0.w = pk2(ra1.z, ra1.w);
    w1.x = pk2(ra2.x, ra2.y); w1.y = pk2(ra2.z, ra2.w);
    w1.z = pk2(ra3.x, ra3.y); w1.w = pk2(ra3.z, ra3.w);
    ((uint4*)lawr)[0] = w0;
    ((uint4*)(lawr + 8))[0] = w1;
  };

  loadA();
  for (int k = 0; k < 64; ++k) {
    __syncthreads();
    gload16(gb0, lb);
    gload16(gb1, lb + 2048);
    gb0 += 32; gb1 += 32;
    cvtWrite();
    if (k < 63) { ga += 32; loadA(); }
    __syncthreads();
    bf16x8 av[4], bv[4];
#pragma unroll
    for (int mf = 0; mf < 4; ++mf) av[mf] = *(const bf16x8*)(fa + mf * 512);
#pragma unroll
    for (int nf = 0; nf < 4; ++nf) bv[nf] = *(const bf16x8*)(fb + nf * 512);
#pragma unroll
    for (int mf = 0; mf < 4; ++mf)
#pragma unroll
      for (int nf = 0; nf < 4; ++nf)
        acc[mf][nf] = __builtin_amdgcn_mfma_f32_16x16x32_bf16(av[mf], bv[nf], acc[mf][nf], 0, 0, 0);
  }

#pragma unroll
  for (int mf = 0; mf < 4; ++mf) {
    const size_t rb = m0 + wm + mf * 16 + fq * 4;
#pragma unroll
    for (int nf = 0; nf < 4; ++nf) {
      const int gn = n0 + wn + nf * 16 + fr;
      const float bb = bias[gn];
#pragma unroll
      for (int rr = 0; rr < 4; ++rr)
        C[(rb + rr) * (size_t)kNF + gn] = f2bf(acc[mf][nf][rr] + bb);
    }
  }
}

// ---------------- 64x128 GEMM, dbuf 1-barrier, f32 out, optional col stats ----------------
template <int STATS>
__global__ __launch_bounds__(256) void gemm_bt64(
    const u16* __restrict__ A, int lda, const u16* __restrict__ B, int ldb,
    const float* __restrict__ bias, float* __restrict__ C, int ldc, int K,
    float* __restrict__ stats)
{
  __shared__ __align__(16) u16 As[2 * 64 * 32];
  __shared__ __align__(16) u16 Bs[2 * 128 * 32];
  const int bx = blockIdx.x, by = blockIdx.y;
  const size_t m0 = (size_t)bx * 64;
  const int n0 = by * 128;
  const int t = threadIdx.x;
  const int lane = t & 63, wave = t >> 6;
  const int wn = wave * 32;
  const int fr = lane & 15, fq = lane >> 4;

  const int srow = t >> 2, scol = (t & 3) * 8;
  const u16* ga0 = A + (m0 + srow) * (size_t)lda + scol;
  const u16* gb0 = B + (size_t)(n0 + srow) * ldb + scol;
  const u16* gb1 = B + (size_t)(n0 + 64 + srow) * ldb + scol;

  f32x4 acc[4][2] = {};

  gload16(ga0, As + t * 8);
  gload16(gb0, Bs + t * 8);
  gload16(gb1, Bs + t * 8 + 2048);
  ga0 += 32; gb0 += 32; gb1 += 32;
  __syncthreads();

  const int kt = K >> 5;
  for (int k = 0; k < kt; ++k) {
    const int cur = k & 1;
    if (k + 1 < kt) {
      u16* an = As + (cur ^ 1) * 2048;
      u16* bn = Bs + (cur ^ 1) * 4096;
      gload16(ga0, an + t * 8);
      gload16(gb0, bn + t * 8);
      gload16(gb1, bn + t * 8 + 2048);
      ga0 += 32; gb0 += 32; gb1 += 32;
    }
    const u16* fa = As + cur * 2048 + fr * 32 + fq * 8;
    const u16* fb = Bs + cur * 4096 + (wn + fr) * 32 + fq * 8;
    bf16x8 av[4], bv[2];
#pragma unroll
    for (int mf = 0; mf < 4; ++mf) av[mf] = *(const bf16x8*)(fa + mf * 512);
#pragma unroll
    for (int nf = 0; nf < 2; ++nf) bv[nf] = *(const bf16x8*)(fb + nf * 512);
#pragma unroll
    for (int mf = 0; mf < 4; ++mf)
#pragma unroll
      for (int nf = 0; nf < 2; ++nf)
        acc[mf][nf] = __builtin_amdgcn_mfma_f32_16x16x32_bf16(av[mf], bv[nf], acc[mf][nf], 0, 0, 0);
    __syncthreads();
  }

  float cs[2] = {}, cs2[2] = {};
#pragma unroll
  for (int mf = 0; mf < 4; ++mf) {
    const size_t rb = m0 + mf * 16 + fq * 4;
#pragma unroll
    for (int nf = 0; nf < 2; ++nf) {
      const int gn = n0 + wn + nf * 16 + fr;
      const float bb = bias[gn];
#pragma unroll
      for (int rr = 0; rr < 4; ++rr) {
        const float vv = acc[mf][nf][rr] + bb;
        C[(rb + rr) * (size_t)ldc + gn] = vv;
        if (STATS) { cs[nf] += vv; cs2[nf] += vv * vv; }
      }
    }
  }
  if (STATS) {
    const int f = (int)(m0 >> 14);
#pragma unroll
    for (int nf = 0; nf < 2; ++nf) {
      float s = cs[nf], s2 = cs2[nf];
      s += __shfl_down(s, 32); s2 += __shfl_down(s2, 32);
      s += __shfl_down(s, 16); s2 += __shfl_down(s2, 16);
      if (fq == 0) {
        const int gn = n0 + wn + nf * 16 + fr;
        atomicAdd(&stats[(f * 128 + gn) * 2 + 0], s);
        atomicAdd(&stats[(f * 128 + gn) * 2 + 1], s2);
      }
    }
  }
}

// ---------------- fused fuse-GEMM: flattened (f,k) pipeline, dbuf 1-barrier ----------------
__global__ __launch_bounds__(256) void gemm_fuse64(
    const u16* __restrict__ feats, const u16* __restrict__ w1,
    const float* __restrict__ scores, const float* __restrict__ b1,
    float* __restrict__ fuse, float* __restrict__ fstats)
{
  __shared__ __align__(16) u16 As[2 * 64 * 32];
  __shared__ __align__(16) u16 Bs[2 * 128 * 32];
  const int bx = blockIdx.x, by = blockIdx.y;
  const size_t m0 = (size_t)bx * 64;
  const int n0 = by * 128;
  const int t = threadIdx.x;
  const int lane = t & 63, wave = t >> 6;
  const int wn = wave * 32;
  const int fr = lane & 15, fq = lane >> 4;
  const int srow = t >> 2, scol = (t & 3) * 8;

  const u16* ga0; const u16* gb0; const u16* gb1;
  auto setf = [&](int f) {
    ga0 = feats + (size_t)f * kB * kNF + (m0 + srow) * (size_t)kNF + scol;
    gb0 = w1 + f * kNF + (size_t)(n0 + srow) * 2304 + scol;
    gb1 = gb0 + (size_t)64 * 2304;
  };

  const f32x4 vzero = {};
  f32x4 acc[4][2] = {}, tot[4][2] = {};

  setf(0);
  gload16(ga0, As + t * 8);
  gload16(gb0, Bs + t * 8);
  gload16(gb1, Bs + t * 8 + 2048);
  ga0 += 32; gb0 += 32; gb1 += 32;
  int pf = 0, pk = 1;
  int ck = 0, cf = 0;
  __syncthreads();

  for (int s = 0; s < 72; ++s) {
    const int cur = s & 1;
    if (s < 71) {
      u16* an = As + (cur ^ 1) * 2048;
      u16* bn = Bs + (cur ^ 1) * 4096;
      gload16(ga0, an + t * 8);
      gload16(gb0, bn + t * 8);
      gload16(gb1, bn + t * 8 + 2048);
      if (++pk == 24) { pk = 0; ++pf; if (pf < 3) setf(pf); }
      else { ga0 += 32; gb0 += 32; gb1 += 32; }
    }
    const u16* fa = As + cur * 2048 + fr * 32 + fq * 8;
    const u16* fb = Bs + cur * 4096 + (wn + fr) * 32 + fq * 8;
    bf16x8 av[4], bv[2];
#pragma unroll
    for (int mf = 0; mf < 4; ++mf) av[mf] = *(const bf16x8*)(fa + mf * 512);
#pragma unroll
    for (int nf = 0; nf < 2; ++nf) bv[nf] = *(const bf16x8*)(fb + nf * 512);
#pragma unroll
    for (int mf = 0; mf < 4; ++mf)
#pragma unroll
      for (int nf = 0; nf < 2; ++nf)
        acc[mf][nf] = __builtin_amdgcn_mfma_f32_16x16x32_bf16(av[mf], bv[nf], acc[mf][nf], 0, 0, 0);
    if (++ck == 24) {
      ck = 0;
#pragma unroll
      for (int mf = 0; mf < 4; ++mf) {
        const size_t rb = m0 + mf * 16 + fq * 4;
#pragma unroll
        for (int rr = 0; rr < 4; ++rr) {
          const float sv = scores[(rb + rr) * 3 + cf];
#pragma unroll
          for (int nf = 0; nf < 2; ++nf) tot[mf][nf][rr] += sv * acc[mf][nf][rr];
        }
      }
#pragma unroll
      for (int mf = 0; mf < 4; ++mf)
#pragma unroll
        for (int nf = 0; nf < 2; ++nf) acc[mf][nf] = vzero;
      ++cf;
    }
    __syncthreads();
  }

  float cs[2] = {}, cs2[2] = {};
#pragma unroll
  for (int mf = 0; mf < 4; ++mf) {
    const size_t rb = m0 + mf * 16 + fq * 4;
#pragma unroll
    for (int nf = 0; nf < 2; ++nf) {
      const int gn = n0 + wn + nf * 16 + fr;
      const float bb = b1[gn];
#pragma unroll
      for (int rr = 0; rr < 4; ++rr) {
        const float vv = tot[mf][nf][rr] + bb;
        fuse[(rb + rr) * 256 + gn] = vv;
        cs[nf] += vv; cs2[nf] += vv * vv;
      }
    }
  }
#pragma unroll
  for (int nf = 0; nf < 2; ++nf) {
    float s = cs[nf], s2 = cs2[nf];
    s += __shfl_down(s, 32); s2 += __shfl_down(s2, 32);
    s += __shfl_down(s, 16); s2 += __shfl_down(s2, 16);
    if (fq == 0) {
      const int gn = n0 + wn + nf * 16 + fr;
      atomicAdd(&fstats[gn * 2 + 0], s);
      atomicAdd(&fstats[gn * 2 + 1], s2);
    }
  }
}

// ---------------- attention scores: bn+gelu+dot (x3) + softmax ----------------
__global__ __launch_bounds__(64) void att_kernel(
    const float* __restrict__ H, const float* __restrict__ stats,
    const float* __restrict__ ga, const float* __restrict__ bba,
    const float* __restrict__ Wa2, const float* __restrict__ ba2,
    float* __restrict__ scores)
{
  const int i = blockIdx.x, l = threadIdx.x;
  float d[3];
#pragma unroll
  for (int f = 0; f < 3; ++f) {
    float part = 0.f;
#pragma unroll
    for (int h = 0; h < 2; ++h) {
      const int c = l + h * 64;
      const float sum = stats[(f * 128 + c) * 2 + 0];
      const float sq  = stats[(f * 128 + c) * 2 + 1];
      const float m = sum * (1.f / kB);
      const float var = sq * (1.f / kB) - m * m;
      const float rs = rsqrtf(var + kEps);
      const float x = H[((size_t)f * kB + i) * 128 + c];
      const float xn = (x - m) * rs * ga[c] + bba[c];
      const float ge = 0.5f * xn * (1.f + erff(xn * 0.70710678118f));
      part += ge * Wa2[c];
    }
#pragma unroll
    for (int off = 32; off > 0; off >>= 1) part += __shfl_down(part, off);
    d[f] = part;
  }
  if (l == 0) {
    const float b2 = ba2[0];
    float d0 = d[0] + b2, d1 = d[1] + b2, d2 = d[2] + b2;
    const float mx = fmaxf(d0, fmaxf(d1, d2));
    const float e0 = expf(d0 - mx), e1 = expf(d1 - mx), e2 = expf(d2 - mx);
    const float inv = 1.f / (e0 + e1 + e2);
    scores[i * 3 + 0] = e0 * inv;
    scores[i * 3 + 1] = e1 * inv;
    scores[i * 3 + 2] = e2 * inv;
  }
}

// ---------------- final: bn + relu + [256 -> 26] ----------------
__global__ __launch_bounds__(64) void final_kernel(
    const float* __restrict__ fuse, const float* __restrict__ fstats,
    const float* __restrict__ g1, const float* __restrict__ be1,
    const float* __restrict__ Wcat, const float* __restrict__ bcat,
    float* __restrict__ out)
{
  const int i = blockIdx.x, l = threadIdx.x;
  __shared__ float row[256];
#pragma unroll
  for (int h = 0; h < 4; ++h) {
    const int c = l + h * 64;
    const float sum = fstats[c * 2 + 0], sq = fstats[c * 2 + 1];
    const float m = sum * (1.f / kB);
    const float var = sq * (1.f / kB) - m * m;
    const float rs = rsqrtf(var + kEps);
    const float v = (fuse[(size_t)i * 256 + c] - m) * rs * g1[c] + be1[c];
    row[c] = fmaxf(v, 0.f);
  }
  __syncthreads();
  if (l < 26) {
    float acc = bcat[l];
    const float* w = Wcat + l * 256;
    for (int k2 = 0; k2 < 256; ++k2) acc += row[k2] * w[k2];
    out[(size_t)i * 26 + l] = acc;
  }
}

extern "C" void kernel_launch(void* const* d_in, const int* in_sizes, int n_in,
                              void* d_out, int out_size, void* d_ws, size_t ws_size,
                              hipStream_t stream) {
  (void)in_sizes; (void)n_in; (void)out_size; (void)ws_size;
  const float* xc   = (const float*)d_in[0];
  const float* xb   = (const float*)d_in[1];
  const float* xf   = (const float*)d_in[2];
  const float* Wc   = (const float*)d_in[3];
  const float* bc   = (const float*)d_in[4];
  const float* Wa1  = (const float*)d_in[5];
  const float* ba1  = (const float*)d_in[6];
  const float* ga   = (const float*)d_in[7];
  const float* bba  = (const float*)d_in[8];
  const float* Wa2  = (const float*)d_in[9];
  const float* ba2  = (const float*)d_in[10];
  const float* W1   = (const float*)d_in[11];
  const float* b1   = (const float*)d_in[12];
  const float* g1   = (const float*)d_in[13];
  const float* be1  = (const float*)d_in[14];
  const float* Wcat = (const float*)d_in[15];
  const float* bcat = (const float*)d_in[16];
  float* out = (float*)d_out;

  char* ws = (char*)d_ws;
  u16* feats   = (u16*)(ws + OFF_FEATS);
  float* H     = (float*)(ws + OFF_X);     // [3*B][128] f32
  u16* wcbf    = (u16*)(ws + OFF_WCBF);
  u16* wa1bf   = (u16*)(ws + OFF_WA1BF);
  u16* w1bf    = (u16*)(ws + OFF_W1BF);
  float* fuse  = (float*)(ws + OFF_FUSE);
  float* scores= (float*)(ws + OFF_SCORES);
  float* hst   = (float*)(ws + OFF_STATS);
  float* fst   = (float*)(ws + OFF_STATS + 3072);

  hipMemsetAsync(ws + OFF_STATS, 0, 5120, stream);
  // weights -> bf16 (tiny)
  prep_w<<<276, 256, 0, stream>>>(Wc, Wa1, W1, wcbf, wa1bf, w1bf);
  // GEMM1 (fp32 xc staged in-kernel) + xb/xf conversion blocks
  gemm_mega<<<2816, 256, 0, stream>>>(xc, wcbf, bc, feats, xb, xf, feats);
  // H = feats @ Wa1^T + ba1  (M=49152, N=128, K=768) -> f32, fused column stats
  gemm_bt64<1><<<dim3(768, 1), 256, 0, stream>>>(feats, kNF, wa1bf, kNF, ba1, H, 128, kNF, hst);
  att_kernel<<<kB, 64, 0, stream>>>(H, hst, ga, bba, Wa2, ba2, scores);
  // fuse = sum_f s_f*(feat_f @ W1_f^T) + b1  (M=16384, N=256, 3x K=768), fused stats
  gemm_fuse64<<<dim3(256, 2), 256, 0, stream>>>(feats, w1bf, scores, b1, fuse, fst);
  final_kernel<<<kB, 64, 0, stream>>>(fuse, fst, g1, be1, Wcat, bcat, out);
}

// Round 8
// 285.553 us; speedup vs baseline: 1.0695x; 1.0695x over previous
//
#include <hip/hip_runtime.h>
#include <hip/hip_bf16.h>
#include <stdint.h>

typedef float f32x4 __attribute__((ext_vector_type(4)));
typedef short bf16x8 __attribute__((ext_vector_type(8)));
typedef unsigned short u16;

static constexpr int kB  = 16384;
static constexpr int kDC = 2048;
static constexpr int kNF = 768;
static constexpr float kEps = 1e-5f;

// ---- workspace layout (bytes). Region X at OFF_X reused by liveness:
//  axbf (prep->gemm1) -> H (gemmH->att)
static constexpr size_t OFF_FEATS  = 0;                       // [3][B][768] bf16
static constexpr size_t OFF_X      = 75497472;                // axbf 67MB / H [3*B][128] f32
static constexpr size_t OFF_WCBF   = OFF_X + 67108864;
static constexpr size_t OFF_WA1BF  = OFF_WCBF + 3145728;
static constexpr size_t OFF_W1BF   = OFF_WA1BF + 196608;
static constexpr size_t OFF_FUSE   = OFF_W1BF + 1179648;      // [B][256] f32
static constexpr size_t OFF_SCORES = OFF_FUSE + 16777216;     // [B][3] f32
static constexpr size_t OFF_STATS  = OFF_SCORES + 196608;     // 3072 + 2048

static __device__ __forceinline__ u16 f2bf(float x) {
  union { float f; unsigned u; } c; c.f = x;
  unsigned r = c.u + 0x7fffu + ((c.u >> 16) & 1u);
  return (u16)(r >> 16);
}

// batched convert: force all 8 loads in flight before any cvt/store
// (sched_barrier(0) pins program order; compiler was re-serializing to save VGPRs)
static __device__ __forceinline__ void cvt8x4(const float* __restrict__ in,
                                              u16* __restrict__ out, long base) {
  float4 f[8];
#pragma unroll
  for (int i = 0; i < 8; ++i) f[i] = ((const float4*)in)[base + i * 256];
  __builtin_amdgcn_sched_barrier(0);
#pragma unroll
  for (int i = 0; i < 8; ++i)
    ((ushort4*)out)[base + i * 256] =
        make_ushort4(f2bf(f[i].x), f2bf(f[i].y), f2bf(f[i].z), f2bf(f[i].w));
}

// ---------------- prep: fp32 -> bf16 for xc, Wc, Wa1, W1 (+ stats zero) ----------------
// 256 threads x 8 float4. xc 8,388,608 f4 -> 4096 blk | Wc 393,216 -> 192 | Wa1 24,576 -> 12 |
// W1 147,456 -> 72 | stats-zero -> 1   = 4373 blocks
__global__ __launch_bounds__(256) void prep_kernel(
    const float* __restrict__ xc, const float* __restrict__ Wc,
    const float* __restrict__ Wa1, const float* __restrict__ W1,
    u16* __restrict__ axbf, u16* __restrict__ wcbf,
    u16* __restrict__ wa1bf, u16* __restrict__ w1bf,
    float* __restrict__ stats)
{
  const int b = blockIdx.x, t = threadIdx.x;
  if (b == 4372) {           // zero 5120 B of stats (hst 3072 + fst 2048)
#pragma unroll
    for (int i = 0; i < 5; ++i) stats[t + i * 256] = 0.f;
    return;
  }
  const float* in; u16* out; long base;
  if (b < 4096)      { in = xc;  out = axbf;  base = (long)b * 2048 + t; }
  else if (b < 4288) { in = Wc;  out = wcbf;  base = (long)(b - 4096) * 2048 + t; }
  else if (b < 4300) { in = Wa1; out = wa1bf; base = (long)(b - 4288) * 2048 + t; }
  else               { in = W1;  out = w1bf;  base = (long)(b - 4300) * 2048 + t; }
  cvt8x4(in, out, base);
}

static __device__ __forceinline__ void gload16(const void* g, void* l) {
  __builtin_amdgcn_global_load_lds(
      (const __attribute__((address_space(1))) void*)g,
      (__attribute__((address_space(3))) void*)l, 16, 0, 0);
}

// ---------------- merged: GEMM1 (ctx) + xb/xf bf16 conversion blocks ----------------
// 1-D grid of 768 + 1536 + 512 = 2816 blocks.
//  id <  768 : GEMM block, bx = id & 127 (M-tile), by = id >> 7 (N-tile, 0..5)
//  id >= 768 : convert blocks (xb: 1536 blocks, xf-repeat: 512 blocks)
__global__ __launch_bounds__(256) void gemm_ctx_conv(
    const u16* __restrict__ A, const u16* __restrict__ B,
    const float* __restrict__ bias, u16* __restrict__ C,
    const float* __restrict__ xb, const float* __restrict__ xf,
    u16* __restrict__ feats)
{
  __shared__ __align__(16) u16 As[128 * 32];
  __shared__ __align__(16) u16 Bs[128 * 32];
  const int id = blockIdx.x, t = threadIdx.x;

  if (id >= 768) {
    const int c = id - 768;
    if (c < 1536) {                       // xb -> feats[1]
      cvt8x4(xb, feats + (size_t)kB * kNF, (long)c * 2048 + t);
    } else {                              // xf -> feats[2] with repeat(3)
      const long base = (long)(c - 1536) * 2048 + t;
      float4 f[8];
#pragma unroll
      for (int i = 0; i < 8; ++i) f[i] = ((const float4*)xf)[base + i * 256];
      __builtin_amdgcn_sched_barrier(0);
#pragma unroll
      for (int i = 0; i < 8; ++i) {
        const long v = base + i * 256;
        u16 e0 = f2bf(f[i].x), e1 = f2bf(f[i].y), e2 = f2bf(f[i].z), e3 = f2bf(f[i].w);
        size_t p = (size_t)v * 4;
        size_t row = p >> 8;
        int col = (int)(p & 255);
        u16* o = feats + (size_t)2 * kB * kNF + row * kNF + col * 3;
        ushort4* o4 = (ushort4*)o;
        o4[0] = make_ushort4(e0, e0, e0, e1);
        o4[1] = make_ushort4(e1, e1, e2, e2);
        o4[2] = make_ushort4(e2, e3, e3, e3);
      }
    }
    return;
  }

  // ---- GEMM path: m97 structure, C = A @ B^T + bias -> bf16 ----
  const int bx = id & 127, by = id >> 7;
  const size_t m0 = (size_t)bx * 128;
  const int n0 = by * 128;
  const int lane = t & 63, wave = t >> 6;
  const int wm = (wave >> 1) * 64, wn = (wave & 1) * 64;
  const int fr = lane & 15, fq = lane >> 4;

  const int srow = t >> 2, scol = (t & 3) * 8;
  const u16* ga0 = A + (m0 + srow) * (size_t)kDC + scol;
  const u16* ga1 = A + (m0 + 64 + srow) * (size_t)kDC + scol;
  const u16* gb0 = B + (size_t)(n0 + srow) * kDC + scol;
  const u16* gb1 = B + (size_t)(n0 + 64 + srow) * kDC + scol;
  u16* la = As + t * 8;
  u16* lb = Bs + t * 8;
  const u16* fa = As + (wm + fr) * 32 + fq * 8;
  const u16* fb = Bs + (wn + fr) * 32 + fq * 8;

  f32x4 acc[4][4] = {};

  for (int k = 0; k < 64; ++k) {
    __syncthreads();
    gload16(ga0, la);
    gload16(ga1, la + 2048);
    gload16(gb0, lb);
    gload16(gb1, lb + 2048);
    ga0 += 32; ga1 += 32; gb0 += 32; gb1 += 32;
    __syncthreads();
    bf16x8 av[4], bv[4];
#pragma unroll
    for (int mf = 0; mf < 4; ++mf) av[mf] = *(const bf16x8*)(fa + mf * 512);
#pragma unroll
    for (int nf = 0; nf < 4; ++nf) bv[nf] = *(const bf16x8*)(fb + nf * 512);
#pragma unroll
    for (int mf = 0; mf < 4; ++mf)
#pragma unroll
      for (int nf = 0; nf < 4; ++nf)
        acc[mf][nf] = __builtin_amdgcn_mfma_f32_16x16x32_bf16(av[mf], bv[nf], acc[mf][nf], 0, 0, 0);
  }

#pragma unroll
  for (int mf = 0; mf < 4; ++mf) {
    const size_t rb = m0 + wm + mf * 16 + fq * 4;
#pragma unroll
    for (int nf = 0; nf < 4; ++nf) {
      const int gn = n0 + wn + nf * 16 + fr;
      const float bb = bias[gn];
#pragma unroll
      for (int rr = 0; rr < 4; ++rr)
        C[(rb + rr) * (size_t)kNF + gn] = f2bf(acc[mf][nf][rr] + bb);
    }
  }
}

// ---------------- 64x128 GEMM, dbuf 1-barrier, f32 out, optional col stats ----------------
template <int STATS>
__global__ __launch_bounds__(256) void gemm_bt64(
    const u16* __restrict__ A, int lda, const u16* __restrict__ B, int ldb,
    const float* __restrict__ bias, float* __restrict__ C, int ldc, int K,
    float* __restrict__ stats)
{
  __shared__ __align__(16) u16 As[2 * 64 * 32];
  __shared__ __align__(16) u16 Bs[2 * 128 * 32];
  const int bx = blockIdx.x, by = blockIdx.y;
  const size_t m0 = (size_t)bx * 64;
  const int n0 = by * 128;
  const int t = threadIdx.x;
  const int lane = t & 63, wave = t >> 6;
  const int wn = wave * 32;
  const int fr = lane & 15, fq = lane >> 4;

  const int srow = t >> 2, scol = (t & 3) * 8;
  const u16* ga0 = A + (m0 + srow) * (size_t)lda + scol;
  const u16* gb0 = B + (size_t)(n0 + srow) * ldb + scol;
  const u16* gb1 = B + (size_t)(n0 + 64 + srow) * ldb + scol;

  f32x4 acc[4][2] = {};

  gload16(ga0, As + t * 8);
  gload16(gb0, Bs + t * 8);
  gload16(gb1, Bs + t * 8 + 2048);
  ga0 += 32; gb0 += 32; gb1 += 32;
  __syncthreads();

  const int kt = K >> 5;
  for (int k = 0; k < kt; ++k) {
    const int cur = k & 1;
    if (k + 1 < kt) {
      u16* an = As + (cur ^ 1) * 2048;
      u16* bn = Bs + (cur ^ 1) * 4096;
      gload16(ga0, an + t * 8);
      gload16(gb0, bn + t * 8);
      gload16(gb1, bn + t * 8 + 2048);
      ga0 += 32; gb0 += 32; gb1 += 32;
    }
    const u16* fa = As + cur * 2048 + fr * 32 + fq * 8;
    const u16* fb = Bs + cur * 4096 + (wn + fr) * 32 + fq * 8;
    bf16x8 av[4], bv[2];
#pragma unroll
    for (int mf = 0; mf < 4; ++mf) av[mf] = *(const bf16x8*)(fa + mf * 512);
#pragma unroll
    for (int nf = 0; nf < 2; ++nf) bv[nf] = *(const bf16x8*)(fb + nf * 512);
#pragma unroll
    for (int mf = 0; mf < 4; ++mf)
#pragma unroll
      for (int nf = 0; nf < 2; ++nf)
        acc[mf][nf] = __builtin_amdgcn_mfma_f32_16x16x32_bf16(av[mf], bv[nf], acc[mf][nf], 0, 0, 0);
    __syncthreads();
  }

  float cs[2] = {}, cs2[2] = {};
#pragma unroll
  for (int mf = 0; mf < 4; ++mf) {
    const size_t rb = m0 + mf * 16 + fq * 4;
#pragma unroll
    for (int nf = 0; nf < 2; ++nf) {
      const int gn = n0 + wn + nf * 16 + fr;
      const float bb = bias[gn];
#pragma unroll
      for (int rr = 0; rr < 4; ++rr) {
        const float vv = acc[mf][nf][rr] + bb;
        C[(rb + rr) * (size_t)ldc + gn] = vv;
        if (STATS) { cs[nf] += vv; cs2[nf] += vv * vv; }
      }
    }
  }
  if (STATS) {
    const int f = (int)(m0 >> 14);
#pragma unroll
    for (int nf = 0; nf < 2; ++nf) {
      float s = cs[nf], s2 = cs2[nf];
      s += __shfl_down(s, 32); s2 += __shfl_down(s2, 32);
      s += __shfl_down(s, 16); s2 += __shfl_down(s2, 16);
      if (fq == 0) {
        const int gn = n0 + wn + nf * 16 + fr;
        atomicAdd(&stats[(f * 128 + gn) * 2 + 0], s);
        atomicAdd(&stats[(f * 128 + gn) * 2 + 1], s2);
      }
    }
  }
}

// ---------------- fused fuse-GEMM: flattened (f,k) pipeline, dbuf 1-barrier ----------------
__global__ __launch_bounds__(256) void gemm_fuse64(
    const u16* __restrict__ feats, const u16* __restrict__ w1,
    const float* __restrict__ scores, const float* __restrict__ b1,
    float* __restrict__ fuse, float* __restrict__ fstats)
{
  __shared__ __align__(16) u16 As[2 * 64 * 32];
  __shared__ __align__(16) u16 Bs[2 * 128 * 32];
  const int bx = blockIdx.x, by = blockIdx.y;
  const size_t m0 = (size_t)bx * 64;
  const int n0 = by * 128;
  const int t = threadIdx.x;
  const int lane = t & 63, wave = t >> 6;
  const int wn = wave * 32;
  const int fr = lane & 15, fq = lane >> 4;
  const int srow = t >> 2, scol = (t & 3) * 8;

  const u16* ga0; const u16* gb0; const u16* gb1;
  auto setf = [&](int f) {
    ga0 = feats + (size_t)f * kB * kNF + (m0 + srow) * (size_t)kNF + scol;
    gb0 = w1 + f * kNF + (size_t)(n0 + srow) * 2304 + scol;
    gb1 = gb0 + (size_t)64 * 2304;
  };

  const f32x4 vzero = {};
  f32x4 acc[4][2] = {}, tot[4][2] = {};

  setf(0);
  gload16(ga0, As + t * 8);
  gload16(gb0, Bs + t * 8);
  gload16(gb1, Bs + t * 8 + 2048);
  ga0 += 32; gb0 += 32; gb1 += 32;
  int pf = 0, pk = 1;
  int ck = 0, cf = 0;
  __syncthreads();

  for (int s = 0; s < 72; ++s) {
    const int cur = s & 1;
    if (s < 71) {
      u16* an = As + (cur ^ 1) * 2048;
      u16* bn = Bs + (cur ^ 1) * 4096;
      gload16(ga0, an + t * 8);
      gload16(gb0, bn + t * 8);
      gload16(gb1, bn + t * 8 + 2048);
      if (++pk == 24) { pk = 0; ++pf; if (pf < 3) setf(pf); }
      else { ga0 += 32; gb0 += 32; gb1 += 32; }
    }
    const u16* fa = As + cur * 2048 + fr * 32 + fq * 8;
    const u16* fb = Bs + cur * 4096 + (wn + fr) * 32 + fq * 8;
    bf16x8 av[4], bv[2];
#pragma unroll
    for (int mf = 0; mf < 4; ++mf) av[mf] = *(const bf16x8*)(fa + mf * 512);
#pragma unroll
    for (int nf = 0; nf < 2; ++nf) bv[nf] = *(const bf16x8*)(fb + nf * 512);
#pragma unroll
    for (int mf = 0; mf < 4; ++mf)
#pragma unroll
      for (int nf = 0; nf < 2; ++nf)
        acc[mf][nf] = __builtin_amdgcn_mfma_f32_16x16x32_bf16(av[mf], bv[nf], acc[mf][nf], 0, 0, 0);
    if (++ck == 24) {
      ck = 0;
#pragma unroll
      for (int mf = 0; mf < 4; ++mf) {
        const size_t rb = m0 + mf * 16 + fq * 4;
#pragma unroll
        for (int rr = 0; rr < 4; ++rr) {
          const float sv = scores[(rb + rr) * 3 + cf];
#pragma unroll
          for (int nf = 0; nf < 2; ++nf) tot[mf][nf][rr] += sv * acc[mf][nf][rr];
        }
      }
#pragma unroll
      for (int mf = 0; mf < 4; ++mf)
#pragma unroll
        for (int nf = 0; nf < 2; ++nf) acc[mf][nf] = vzero;
      ++cf;
    }
    __syncthreads();
  }

  float cs[2] = {}, cs2[2] = {};
#pragma unroll
  for (int mf = 0; mf < 4; ++mf) {
    const size_t rb = m0 + mf * 16 + fq * 4;
#pragma unroll
    for (int nf = 0; nf < 2; ++nf) {
      const int gn = n0 + wn + nf * 16 + fr;
      const float bb = b1[gn];
#pragma unroll
      for (int rr = 0; rr < 4; ++rr) {
        const float vv = tot[mf][nf][rr] + bb;
        fuse[(rb + rr) * 256 + gn] = vv;
        cs[nf] += vv; cs2[nf] += vv * vv;
      }
    }
  }
#pragma unroll
  for (int nf = 0; nf < 2; ++nf) {
    float s = cs[nf], s2 = cs2[nf];
    s += __shfl_down(s, 32); s2 += __shfl_down(s2, 32);
    s += __shfl_down(s, 16); s2 += __shfl_down(s2, 16);
    if (fq == 0) {
      const int gn = n0 + wn + nf * 16 + fr;
      atomicAdd(&fstats[gn * 2 + 0], s);
      atomicAdd(&fstats[gn * 2 + 1], s2);
    }
  }
}

// ---------------- attention scores: bn+gelu+dot (x3) + softmax ----------------
__global__ __launch_bounds__(64) void att_kernel(
    const float* __restrict__ H, const float* __restrict__ stats,
    const float* __restrict__ ga, const float* __restrict__ bba,
    const float* __restrict__ Wa2, const float* __restrict__ ba2,
    float* __restrict__ scores)
{
  const int i = blockIdx.x, l = threadIdx.x;
  float d[3];
#pragma unroll
  for (int f = 0; f < 3; ++f) {
    float part = 0.f;
#pragma unroll
    for (int h = 0; h < 2; ++h) {
      const int c = l + h * 64;
      const float sum = stats[(f * 128 + c) * 2 + 0];
      const float sq  = stats[(f * 128 + c) * 2 + 1];
      const float m = sum * (1.f / kB);
      const float var = sq * (1.f / kB) - m * m;
      const float rs = rsqrtf(var + kEps);
      const float x = H[((size_t)f * kB + i) * 128 + c];
      const float xn = (x - m) * rs * ga[c] + bba[c];
      const float ge = 0.5f * xn * (1.f + erff(xn * 0.70710678118f));
      part += ge * Wa2[c];
    }
#pragma unroll
    for (int off = 32; off > 0; off >>= 1) part += __shfl_down(part, off);
    d[f] = part;
  }
  if (l == 0) {
    const float b2 = ba2[0];
    float d0 = d[0] + b2, d1 = d[1] + b2, d2 = d[2] + b2;
    const float mx = fmaxf(d0, fmaxf(d1, d2));
    const float e0 = expf(d0 - mx), e1 = expf(d1 - mx), e2 = expf(d2 - mx);
    const float inv = 1.f / (e0 + e1 + e2);
    scores[i * 3 + 0] = e0 * inv;
    scores[i * 3 + 1] = e1 * inv;
    scores[i * 3 + 2] = e2 * inv;
  }
}

// ---------------- final: bn + relu + [256 -> 26] ----------------
__global__ __launch_bounds__(64) void final_kernel(
    const float* __restrict__ fuse, const float* __restrict__ fstats,
    const float* __restrict__ g1, const float* __restrict__ be1,
    const float* __restrict__ Wcat, const float* __restrict__ bcat,
    float* __restrict__ out)
{
  const int i = blockIdx.x, l = threadIdx.x;
  __shared__ float row[256];
#pragma unroll
  for (int h = 0; h < 4; ++h) {
    const int c = l + h * 64;
    const float sum = fstats[c * 2 + 0], sq = fstats[c * 2 + 1];
    const float m = sum * (1.f / kB);
    const float var = sq * (1.f / kB) - m * m;
    const float rs = rsqrtf(var + kEps);
    const float v = (fuse[(size_t)i * 256 + c] - m) * rs * g1[c] + be1[c];
    row[c] = fmaxf(v, 0.f);
  }
  __syncthreads();
  if (l < 26) {
    float acc = bcat[l];
    const float* w = Wcat + l * 256;
    for (int k2 = 0; k2 < 256; ++k2) acc += row[k2] * w[k2];
    out[(size_t)i * 26 + l] = acc;
  }
}

extern "C" void kernel_launch(void* const* d_in, const int* in_sizes, int n_in,
                              void* d_out, int out_size, void* d_ws, size_t ws_size,
                              hipStream_t stream) {
  (void)in_sizes; (void)n_in; (void)out_size; (void)ws_size;
  const float* xc   = (const float*)d_in[0];
  const float* xb   = (const float*)d_in[1];
  const float* xf   = (const float*)d_in[2];
  const float* Wc   = (const float*)d_in[3];
  const float* bc   = (const float*)d_in[4];
  const float* Wa1  = (const float*)d_in[5];
  const float* ba1  = (const float*)d_in[6];
  const float* ga   = (const float*)d_in[7];
  const float* bba  = (const float*)d_in[8];
  const float* Wa2  = (const float*)d_in[9];
  const float* ba2  = (const float*)d_in[10];
  const float* W1   = (const float*)d_in[11];
  const float* b1   = (const float*)d_in[12];
  const float* g1   = (const float*)d_in[13];
  const float* be1  = (const float*)d_in[14];
  const float* Wcat = (const float*)d_in[15];
  const float* bcat = (const float*)d_in[16];
  float* out = (float*)d_out;

  char* ws = (char*)d_ws;
  u16* feats   = (u16*)(ws + OFF_FEATS);
  u16* axbf    = (u16*)(ws + OFF_X);       // region X use #1 (xc bf16)
  float* H     = (float*)(ws + OFF_X);     // region X use #2 ([3*B][128] f32)
  u16* wcbf    = (u16*)(ws + OFF_WCBF);
  u16* wa1bf   = (u16*)(ws + OFF_WA1BF);
  u16* w1bf    = (u16*)(ws + OFF_W1BF);
  float* fuse  = (float*)(ws + OFF_FUSE);
  float* scores= (float*)(ws + OFF_SCORES);
  float* hst   = (float*)(ws + OFF_STATS);
  float* fst   = (float*)(ws + OFF_STATS + 3072);

  // xc + weights -> bf16, and zero stats (block 4372)
  prep_kernel<<<4373, 256, 0, stream>>>(xc, Wc, Wa1, W1, axbf, wcbf, wa1bf, w1bf, hst);
  // ctx GEMM (M=16384,N=768,K=2048) -> feats[0], overlapped with xb/xf conversion blocks
  gemm_ctx_conv<<<2816, 256, 0, stream>>>(axbf, wcbf, bc, feats, xb, xf, feats);
  // H = feats @ Wa1^T + ba1  (M=49152, N=128, K=768) -> f32, fused column stats
  gemm_bt64<1><<<dim3(768, 1), 256, 0, stream>>>(feats, kNF, wa1bf, kNF, ba1, H, 128, kNF, hst);
  att_kernel<<<kB, 64, 0, stream>>>(H, hst, ga, bba, Wa2, ba2, scores);
  // fuse = sum_f s_f*(feat_f @ W1_f^T) + b1  (M=16384, N=256, 3x K=768), fused stats
  gemm_fuse64<<<dim3(256, 2), 256, 0, stream>>>(feats, w1bf, scores, b1, fuse, fst);
  final_kernel<<<kB, 64, 0, stream>>>(fuse, fst, g1, be1, Wcat, bcat, out);
}